// Round 3
// baseline (456.805 us; speedup 1.0000x reference)
//
#include <hip/hip_runtime.h>

// KV cache scatter update, fused single-pass version:
//   out_k = k_cache with rows pos_ids replaced by k   (same for v)
// Shapes: cache (1, 8, 32768, 128) f32 = 128 MiB each; k/v (1, 8, 2048, 128) f32.
//
// Structure: build inverse map inv[MAX_CTX] in d_ws (inv[p]=j if pos[j]==p else -1),
// then one fused pass over the cache: each float4 slot streams from either the old
// cache or the new k/v, writing the output exactly once.
// Traffic: read 240 MiB (surviving cache rows) + 16 MiB (k/v) + write 256 MiB
//          = 512 MB -> ~81 us at 6.3 TB/s. (Previous copy+scatter: ~576 MB.)

typedef float v4f __attribute__((ext_vector_type(4)));   // native vec: OK for nontemporal builtins

constexpr int  N_KV     = 8;
constexpr int  MAX_CTX  = 32768;
constexpr int  HEAD_DIM = 128;
constexpr int  CHUNK    = 2048;

constexpr long CACHE_ELEMS = (long)N_KV * MAX_CTX * HEAD_DIM;  // 33,554,432 floats
constexpr long CACHE_N4    = CACHE_ELEMS / 4;                  // 8,388,608 v4f
constexpr int  C4          = HEAD_DIM / 4;                     // 32 v4f per row

// inv[p] = -1 for all p. (Cannot rely on 0xAA poison of d_ws: the first
// correctness call's ws contents are not guaranteed.)
__global__ void inv_init_kernel(int* __restrict__ inv) {
    int i = blockIdx.x * blockDim.x + threadIdx.x;
    if (i < MAX_CTX) inv[i] = -1;
}

// inv[pos[j]] = j
__global__ void inv_fill_kernel(const int* __restrict__ pos, int* __restrict__ inv) {
    int j = blockIdx.x * blockDim.x + threadIdx.x;
    if (j < CHUNK) inv[pos[j]] = j;
}

// One v4f of k-cache and the matching v4f of v-cache per thread.
__global__ void kv_fused_kernel(const v4f* __restrict__ kc,
                                const v4f* __restrict__ vc,
                                const v4f* __restrict__ k,
                                const v4f* __restrict__ v,
                                const int* __restrict__ inv,
                                v4f* __restrict__ out_k,
                                v4f* __restrict__ out_v) {
    long i = (long)blockIdx.x * blockDim.x + threadIdx.x;
    if (i >= CACHE_N4) return;
    int  col = (int)(i & (C4 - 1));       // v4f column within 128-dim row
    long r   = i >> 5;                    // head*MAX_CTX + ctx_row
    int  row = (int)(r & (MAX_CTX - 1));  // ctx position
    int  h   = (int)(r >> 15);            // kv head
    int  j   = inv[row];                  // source chunk row, or -1 (L2-resident)

    v4f a, b;
    if (j >= 0) {
        long s = ((long)h * CHUNK + j) * C4 + col;
        a = k[s];
        b = v[s];
    } else {
        a = __builtin_nontemporal_load(&kc[i]);
        b = __builtin_nontemporal_load(&vc[i]);
    }
    __builtin_nontemporal_store(a, &out_k[i]);
    __builtin_nontemporal_store(b, &out_v[i]);
}

extern "C" void kernel_launch(void* const* d_in, const int* in_sizes, int n_in,
                              void* d_out, int out_size, void* d_ws, size_t ws_size,
                              hipStream_t stream) {
    const v4f* k_cache = (const v4f*)d_in[0];
    const v4f* v_cache = (const v4f*)d_in[1];
    const int* pos     = (const int*)d_in[2];
    const v4f* k       = (const v4f*)d_in[3];
    const v4f* v       = (const v4f*)d_in[4];

    float* out   = (float*)d_out;
    v4f*   out_k = (v4f*)out;
    v4f*   out_v = (v4f*)(out + CACHE_ELEMS);

    int* inv = (int*)d_ws;   // MAX_CTX ints = 128 KB

    inv_init_kernel<<<MAX_CTX / 256, 256, 0, stream>>>(inv);
    inv_fill_kernel<<<CHUNK / 256, 256, 0, stream>>>(pos, inv);

    {
        int  block = 256;
        long grid  = (CACHE_N4 + block - 1) / block;   // 32768 blocks
        kv_fused_kernel<<<(int)grid, block, 0, stream>>>(k_cache, v_cache, k, v,
                                                         inv, out_k, out_v);
    }
}

// Round 4
// 448.089 us; speedup vs baseline: 1.0195x; 1.0195x over previous
//
#include <hip/hip_runtime.h>

// KV cache scatter update:
//   out_k = k_cache; out_k[:, :, pos_ids, :] = k   (same for v)
// Shapes: cache (1, 8, 32768, 128) f32 = 128 MiB each; k/v (1, 8, 2048, 128) f32.
//
// Structure (best measured, R1): bulk copy both caches, then scatter the 2048
// new rows per head over them. Mandatory traffic ~537 MB (read 268 cache +
// 17 k/v, write 268) -> ~88 us floor at 6.3 TB/s; the double-write of
// scattered rows adds only 17 MB (~3 us), cheaper than the inv-map fused
// variant (R3: dependent index load serialized the stream, -9 us regression).

typedef float v4f __attribute__((ext_vector_type(4)));

constexpr int  N_KV     = 8;
constexpr int  MAX_CTX  = 32768;
constexpr int  HEAD_DIM = 128;
constexpr int  CHUNK    = 2048;

constexpr long CACHE_ELEMS = (long)N_KV * MAX_CTX * HEAD_DIM;  // 33,554,432 floats
constexpr long CACHE_N4    = CACHE_ELEMS / 4;                  // 8,388,608 v4f (= 32768 * 256)
constexpr long KV_N4       = (long)N_KV * CHUNK * HEAD_DIM/4;  // 524,288 v4f (= 2048 * 256)
constexpr int  C4          = HEAD_DIM / 4;                     // 32 v4f per row

// Exact-grid copy: one v4f of k-cache + matching v4f of v-cache per thread.
// 64 B/thread, fully coalesced 16 B/lane.
__global__ void kv_copy_kernel(const v4f* __restrict__ kc,
                               const v4f* __restrict__ vc,
                               v4f* __restrict__ out_k,
                               v4f* __restrict__ out_v) {
    long i = (long)blockIdx.x * blockDim.x + threadIdx.x;
    out_k[i] = kc[i];
    out_v[i] = vc[i];
}

// Scatter new rows (runs after copy via stream ordering).
__global__ void kv_scatter_kernel(const v4f* __restrict__ k,
                                  const v4f* __restrict__ v,
                                  const int* __restrict__ pos,
                                  v4f* __restrict__ out_k,
                                  v4f* __restrict__ out_v) {
    long i   = (long)blockIdx.x * blockDim.x + threadIdx.x;
    int  col = (int)(i & (C4 - 1));       // v4f column within 128-dim row
    long r   = i >> 5;                    // flat (head, chunk_row)
    int  row = (int)(r & (CHUNK - 1));    // chunk row -> pos_ids index
    int  h   = (int)(r >> 11);            // kv head
    long p   = (long)pos[row];            // destination context position (L2-resident)
    long o   = ((long)h * MAX_CTX + p) * C4 + col;
    out_k[o] = k[i];
    out_v[o] = v[i];
}

extern "C" void kernel_launch(void* const* d_in, const int* in_sizes, int n_in,
                              void* d_out, int out_size, void* d_ws, size_t ws_size,
                              hipStream_t stream) {
    const v4f* k_cache = (const v4f*)d_in[0];
    const v4f* v_cache = (const v4f*)d_in[1];
    const int* pos     = (const int*)d_in[2];
    const v4f* k       = (const v4f*)d_in[3];
    const v4f* v       = (const v4f*)d_in[4];

    float* out   = (float*)d_out;
    v4f*   out_k = (v4f*)out;
    v4f*   out_v = (v4f*)(out + CACHE_ELEMS);

    // Copy: 8,388,608 v4f pairs -> exactly 32768 blocks x 256 threads.
    kv_copy_kernel<<<(int)(CACHE_N4 / 256), 256, 0, stream>>>(k_cache, v_cache,
                                                              out_k, out_v);
    // Scatter: 524,288 v4f pairs -> exactly 2048 blocks x 256 threads.
    kv_scatter_kernel<<<(int)(KV_N4 / 256), 256, 0, stream>>>(k, v, pos,
                                                              out_k, out_v);
}

// Round 5
// 442.123 us; speedup vs baseline: 1.0332x; 1.0135x over previous
//
#include <hip/hip_runtime.h>

// KV cache scatter update:
//   out_k = k_cache; out_k[:, :, pos_ids, :] = k   (same for v)
// Shapes: cache (1, 8, 32768, 128) f32 = 128 MiB each; k/v (1, 8, 2048, 128) f32.
//
// R5 structure: bulk copy via runtime D2D memcpy nodes (targets the ~85%-peak
// blit/SDMA path vs our compute copy's ~79%), then scatter the 2048 new rows
// per head. Mandatory traffic ~536 MB -> ~85 us floor; harness reset adds a
// fixed ~350 us on top (1 GiB ws poison + out poison + input restores).

typedef float v4f __attribute__((ext_vector_type(4)));

constexpr int  N_KV     = 8;
constexpr int  MAX_CTX  = 32768;
constexpr int  HEAD_DIM = 128;
constexpr int  CHUNK    = 2048;

constexpr long CACHE_ELEMS = (long)N_KV * MAX_CTX * HEAD_DIM;  // 33,554,432 floats
constexpr long CACHE_BYTES = CACHE_ELEMS * 4;                  // 128 MiB
constexpr long KV_N4       = (long)N_KV * CHUNK * HEAD_DIM/4;  // 524,288 v4f (= 2048 * 256)
constexpr int  C4          = HEAD_DIM / 4;                     // 32 v4f per row

// Scatter new rows (runs after the copies via stream ordering).
__global__ void kv_scatter_kernel(const v4f* __restrict__ k,
                                  const v4f* __restrict__ v,
                                  const int* __restrict__ pos,
                                  v4f* __restrict__ out_k,
                                  v4f* __restrict__ out_v) {
    long i   = (long)blockIdx.x * blockDim.x + threadIdx.x;
    int  col = (int)(i & (C4 - 1));       // v4f column within 128-dim row
    long r   = i >> 5;                    // flat (head, chunk_row)
    int  row = (int)(r & (CHUNK - 1));    // chunk row -> pos_ids index
    int  h   = (int)(r >> 11);            // kv head
    long p   = (long)pos[row];            // destination context position (L2-resident)
    long o   = ((long)h * MAX_CTX + p) * C4 + col;
    out_k[o] = k[i];
    out_v[o] = v[i];
}

extern "C" void kernel_launch(void* const* d_in, const int* in_sizes, int n_in,
                              void* d_out, int out_size, void* d_ws, size_t ws_size,
                              hipStream_t stream) {
    const void* k_cache = d_in[0];
    const void* v_cache = d_in[1];
    const int*  pos     = (const int*)d_in[2];
    const v4f*  k       = (const v4f*)d_in[3];
    const v4f*  v       = (const v4f*)d_in[4];

    float* out   = (float*)d_out;
    v4f*   out_k = (v4f*)out;
    v4f*   out_v = (v4f*)(out + CACHE_ELEMS);

    // Bulk copies through the runtime's D2D path (graph-capture legal).
    hipMemcpyAsync(out_k, k_cache, CACHE_BYTES, hipMemcpyDeviceToDevice, stream);
    hipMemcpyAsync(out_v, v_cache, CACHE_BYTES, hipMemcpyDeviceToDevice, stream);

    // Scatter: 524,288 v4f pairs -> exactly 2048 blocks x 256 threads.
    kv_scatter_kernel<<<(int)(KV_N4 / 256), 256, 0, stream>>>(k, v, pos,
                                                              out_k, out_v);
}